// Round 1
// baseline (233.919 us; speedup 1.0000x reference)
//
#include <hip/hip_runtime.h>

typedef float f32x4 __attribute__((ext_vector_type(4)));
typedef short s16x8 __attribute__((ext_vector_type(8)));
typedef short s16x4 __attribute__((ext_vector_type(4)));

static __device__ __forceinline__ short f2b(float f) {
  unsigned u = __builtin_bit_cast(unsigned, f);
  u += 0x7fffu + ((u >> 16) & 1u);   // round-to-nearest-even
  return (short)(u >> 16);
}

// ---- problem constants ----
constexpr int kC  = 256;   // channels
constexpr int kN  = 49;    // tokens per window
constexpr int kNP = 64;    // padded tokens
constexpr int kHD = 32;    // head dim
constexpr float kScale = 0.17677669529663687f;  // 1/sqrt(32)

// ---- LDS geometry (bf16 shorts) ----
constexpr int XT_P  = 264;  // x^T pitch: 528B rows -> 2-way banks on b128
constexpr int QK_P  = 40;   // q/k pitch: 80B rows -> 2-way banks
constexpr int VT_P  = 72;   // v^T pitch: 144B rows -> 2-way banks
constexpr int P_P   = 72;   // P pitch
constexpr int AOT_P = 264;  // attn-out^T pitch
constexpr int R1   = 64 * XT_P * 2;            // 33792: q base (R0 = xT/aoT union)
constexpr int R2   = R1 + 8 * 64 * QK_P * 2;   // 74752: k base
constexpr int R3   = R2 + 8 * 64 * QK_P * 2;   // 115712: vT base
constexpr int SMEM = R3 + 8 * 32 * VT_P * 2;   // 152576 <= 160KB

// ws layout: Wq bf16 [768][256] @0 (393216B), Wp bf16 [256][256] @393216 (131072B),
//            biasx f32 [8][64][64] @524288 (131072B)  -> total 655360B
__global__ void prep_kernel(const float* __restrict__ qw,
                            const float* __restrict__ pw,
                            const float* __restrict__ bt,
                            const int* __restrict__ ri,
                            short* __restrict__ Wq,
                            short* __restrict__ Wp,
                            float* __restrict__ bx) {
  int i = blockIdx.x * 256 + threadIdx.x;
  if (i < 768 * 256) Wq[i] = f2b(qw[i]);
  if (i < 256 * 256) Wp[i] = f2b(pw[i]);
  if (i < 8 * 64 * 64) {
    int h = i >> 12, q = (i >> 6) & 63, k = i & 63;
    float v = -10000.f;                       // masks token padding through softmax
    if (q < kN && k < kN) v = bt[ri[q * kN + k] * 8 + h];
    bx[i] = v;
  }
}

__global__ __launch_bounds__(512, 2) void winattn_kernel(
    const float* __restrict__ x, const float* __restrict__ qkv_b,
    const float* __restrict__ proj_b, const short* __restrict__ Wq,
    const short* __restrict__ Wp, const float* __restrict__ biasx,
    float* __restrict__ out) {
  __shared__ alignas(16) char smem[SMEM];
  short* xT  = (short*)smem;          // [64][264]   (phase 1-2)
  short* aoT = xT;                    // [64][264]   (phase 3b-4, xT dead)
  short* qs  = (short*)(smem + R1);   // [8][64][40] (phase 2-3a)
  short* ks  = (short*)(smem + R2);   // [8][64][40] (phase 2-3a)
  short* vt  = (short*)(smem + R3);   // [8][32][72]
  // P overlays q+k after the S barrier: 8 waves x [64][72] = 73728B <= 81920B

  const int tid  = threadIdx.x;
  const int wv   = tid >> 6;          // wave 0..7
  const int lane = tid & 63;
  const int lg   = lane >> 4;         // lane group 0..3
  const int ln   = lane & 15;
  const size_t wbase = (size_t)blockIdx.x * (kC * kN);

  // ---------- Phase 1: stage x^T (bf16) ----------
  {
    const float* xw = x + wbase;
    for (int i = tid; i < kC * kN; i += 512) {
      int c = i / kN, n = i - c * kN;
      xT[n * XT_P + c] = f2b(xw[i]);          // coalesced global read
    }
    for (int i = tid; i < (kNP - kN) * kC; i += 512) {
      int n = kN + (i >> 8), c = i & 255;
      xT[n * XT_P + c] = 0;                   // zero token padding
    }
  }
  __syncthreads();

  // ---------- Phase 2: qkv = Wq @ x + b   (M=768, K=256, N=64) ----------
  {
    s16x8 Bf[4][8];  // x^T fragments, cached in 128 VGPRs
#pragma unroll
    for (int nt = 0; nt < 4; ++nt)
#pragma unroll
      for (int kk = 0; kk < 8; ++kk)
        Bf[nt][kk] = *(const s16x8*)&xT[(nt * 16 + ln) * XT_P + kk * 32 + lg * 8];

#pragma unroll 1
    for (int i = 0; i < 6; ++i) {
      const int mt = wv * 6 + i, o0 = mt * 16;
      const short* wr = Wq + (size_t)(o0 + ln) * kC;
      s16x8 Af[8];
#pragma unroll
      for (int kk = 0; kk < 8; ++kk) Af[kk] = *(const s16x8*)&wr[kk * 32 + lg * 8];
      f32x4 acc[4] = {};
#pragma unroll
      for (int kk = 0; kk < 8; ++kk)
#pragma unroll
        for (int nt = 0; nt < 4; ++nt)
          acc[nt] = __builtin_amdgcn_mfma_f32_16x16x32_bf16(Af[kk], Bf[nt][kk], acc[nt], 0, 0, 0);

      const int t = o0 >> 8, h = (o0 >> 5) & 7, d0 = (o0 & 31) + lg * 4;
      const f32x4 bq = *(const f32x4*)&qkv_b[o0 + lg * 4];
#pragma unroll
      for (int nt = 0; nt < 4; ++nt) {
        const int n = nt * 16 + ln;
        if (t < 2) {                          // q / k: [h][token][d], packed b64 write
          short* dst = (t == 0 ? qs : ks) + h * (kNP * QK_P) + n * QK_P + d0;
          s16x4 pk;
#pragma unroll
          for (int r = 0; r < 4; ++r) pk[r] = f2b(acc[nt][r] + bq[r]);
          *(s16x4*)dst = pk;
        } else {                              // v transposed: [h][d][token]
#pragma unroll
          for (int r = 0; r < 4; ++r)
            vt[(h * kHD + d0 + r) * VT_P + n] = f2b(acc[nt][r] + bq[r]);
        }
      }
    }
  }
  __syncthreads();

  // ---------- Phase 3: attention, head = wv ----------
  float Ssc[4][4][4];  // [qtile][ktile][reg]
  {
    const short* qh = qs + wv * (kNP * QK_P);
    const short* kh = ks + wv * (kNP * QK_P);
    s16x8 Qf[4], Kf[4];
#pragma unroll
    for (int tI = 0; tI < 4; ++tI) {
      Qf[tI] = *(const s16x8*)&qh[(tI * 16 + ln) * QK_P + lg * 8];
      Kf[tI] = *(const s16x8*)&kh[(tI * 16 + ln) * QK_P + lg * 8];
    }
    const float* bx = biasx + wv * (kNP * kNP);
#pragma unroll
    for (int qt = 0; qt < 4; ++qt)
#pragma unroll
      for (int nt = 0; nt < 4; ++nt) {
        f32x4 a = {};
        a = __builtin_amdgcn_mfma_f32_16x16x32_bf16(Qf[qt], Kf[nt], a, 0, 0, 0);
#pragma unroll
        for (int r = 0; r < 4; ++r) {
          const int qr = qt * 16 + lg * 4 + r;
          Ssc[qt][nt][r] = a[r] * kScale + bx[qr * kNP + nt * 16 + ln];
        }
      }
    // wave-parallel softmax over keys (ktile regs + 16-lane groups)
#pragma unroll
    for (int qt = 0; qt < 4; ++qt)
#pragma unroll
      for (int r = 0; r < 4; ++r) {
        float m = fmaxf(fmaxf(Ssc[qt][0][r], Ssc[qt][1][r]),
                        fmaxf(Ssc[qt][2][r], Ssc[qt][3][r]));
#pragma unroll
        for (int off = 1; off < 16; off <<= 1) m = fmaxf(m, __shfl_xor(m, off));
        float s = 0.f;
#pragma unroll
        for (int nt = 0; nt < 4; ++nt) {
          float p = __expf(Ssc[qt][nt][r] - m);
          Ssc[qt][nt][r] = p;
          s += p;
        }
#pragma unroll
        for (int off = 1; off < 16; off <<= 1) s += __shfl_xor(s, off);
        const float rinv = 1.f / s;
#pragma unroll
        for (int nt = 0; nt < 4; ++nt) Ssc[qt][nt][r] *= rinv;
      }
  }
  __syncthreads();  // all waves finished reading q/k -> safe to overlay with P

  short* Pw = qs + wv * (kNP * P_P);
#pragma unroll
  for (int qt = 0; qt < 4; ++qt)
#pragma unroll
    for (int nt = 0; nt < 4; ++nt)
#pragma unroll
      for (int r = 0; r < 4; ++r)
        Pw[(qt * 16 + lg * 4 + r) * P_P + nt * 16 + ln] = f2b(Ssc[qt][nt][r]);
  __syncthreads();  // (own-wave data; barrier kept for clarity/safety)

  {
    f32x4 O[4][2] = {};
#pragma unroll
    for (int kk = 0; kk < 2; ++kk) {
      s16x8 Vf[2];
#pragma unroll
      for (int dt = 0; dt < 2; ++dt)
        Vf[dt] = *(const s16x8*)&vt[(wv * kHD + dt * 16 + ln) * VT_P + kk * 32 + lg * 8];
#pragma unroll
      for (int qt = 0; qt < 4; ++qt) {
        const s16x8 Pf = *(const s16x8*)&Pw[(qt * 16 + ln) * P_P + kk * 32 + lg * 8];
#pragma unroll
        for (int dt = 0; dt < 2; ++dt)
          O[qt][dt] = __builtin_amdgcn_mfma_f32_16x16x32_bf16(Pf, Vf[dt], O[qt][dt], 0, 0, 0);
      }
    }
    // attn-out^T [token][c], overlays dead x^T
#pragma unroll
    for (int qt = 0; qt < 4; ++qt)
#pragma unroll
      for (int dt = 0; dt < 2; ++dt)
#pragma unroll
        for (int r = 0; r < 4; ++r)
          aoT[(qt * 16 + lg * 4 + r) * AOT_P + wv * kHD + dt * 16 + ln] = f2b(O[qt][dt][r]);
  }
  __syncthreads();

  // ---------- Phase 4: out = Wp @ attn_out + b   (M=256, K=256, N=64) ----------
  {
    s16x8 Bp[4][8];
#pragma unroll
    for (int nt = 0; nt < 4; ++nt)
#pragma unroll
      for (int kk = 0; kk < 8; ++kk)
        Bp[nt][kk] = *(const s16x8*)&aoT[(nt * 16 + ln) * AOT_P + kk * 32 + lg * 8];

#pragma unroll 1
    for (int i = 0; i < 2; ++i) {
      const int mt = wv * 2 + i, o0 = mt * 16;
      const short* wr = Wp + (size_t)(o0 + ln) * kC;
      s16x8 Ap[8];
#pragma unroll
      for (int kk = 0; kk < 8; ++kk) Ap[kk] = *(const s16x8*)&wr[kk * 32 + lg * 8];
      f32x4 acc[4] = {};
#pragma unroll
      for (int kk = 0; kk < 8; ++kk)
#pragma unroll
        for (int nt = 0; nt < 4; ++nt)
          acc[nt] = __builtin_amdgcn_mfma_f32_16x16x32_bf16(Ap[kk], Bp[nt][kk], acc[nt], 0, 0, 0);

      const f32x4 pb = *(const f32x4*)&proj_b[o0 + lg * 4];
#pragma unroll
      for (int nt = 0; nt < 4; ++nt) {
        const int n = nt * 16 + ln;
        if (n < kN) {
#pragma unroll
          for (int r = 0; r < 4; ++r)
            out[wbase + (size_t)(o0 + lg * 4 + r) * kN + n] = acc[nt][r] + pb[r];
        }
      }
    }
  }
}

extern "C" void kernel_launch(void* const* d_in, const int* in_sizes, int n_in,
                              void* d_out, int out_size, void* d_ws, size_t ws_size,
                              hipStream_t stream) {
  (void)in_sizes; (void)n_in; (void)out_size; (void)ws_size;
  const float* x      = (const float*)d_in[0];
  const float* qkv_w  = (const float*)d_in[1];
  const float* qkv_b  = (const float*)d_in[2];
  const float* proj_w = (const float*)d_in[3];
  const float* proj_b = (const float*)d_in[4];
  const float* btab   = (const float*)d_in[5];
  const int*   ridx   = (const int*)d_in[6];

  short* Wq = (short*)d_ws;                     // 393216 B
  short* Wp = (short*)((char*)d_ws + 393216);   // 131072 B
  float* bx = (float*)((char*)d_ws + 524288);   // 131072 B

  prep_kernel<<<768, 256, 0, stream>>>(qkv_w, proj_w, btab, ridx, Wq, Wp, bx);
  winattn_kernel<<<2048, 512, 0, stream>>>(x, qkv_b, proj_b, Wq, Wp, bx, (float*)d_out);
}